// Round 1
// baseline (527.089 us; speedup 1.0000x reference)
//
#include <hip/hip_runtime.h>

#define DIN 128
#define DH 64
#define DOUT 32
#define BN_EPS 1e-5f

// ---------------- CSR build ----------------

__global__ __launch_bounds__(256) void count_k(const int* __restrict__ dst, int* __restrict__ cnt, int E) {
    int i = blockIdx.x * 256 + threadIdx.x;
    if (i < E) atomicAdd(&cnt[dst[i]], 1);
}

__global__ __launch_bounds__(256) void scan_block_k(const int* __restrict__ cnt, int* __restrict__ rp,
                                                    int* __restrict__ bsums, int n) {
    __shared__ int tmp[256];
    int i = blockIdx.x * 256 + threadIdx.x;
    int v = (i < n) ? cnt[i] : 0;
    tmp[threadIdx.x] = v;
    __syncthreads();
    for (int off = 1; off < 256; off <<= 1) {
        int t = (threadIdx.x >= off) ? tmp[threadIdx.x - off] : 0;
        __syncthreads();
        tmp[threadIdx.x] += t;
        __syncthreads();
    }
    if (i < n) rp[i] = tmp[threadIdx.x] - v;   // local exclusive scan
    if (threadIdx.x == 255) bsums[blockIdx.x] = tmp[255];
}

__global__ __launch_bounds__(512) void scan_sums_k(int* __restrict__ bsums, int nb) {
    __shared__ int tmp[512];
    int v = (threadIdx.x < nb) ? bsums[threadIdx.x] : 0;
    tmp[threadIdx.x] = v;
    __syncthreads();
    for (int off = 1; off < 512; off <<= 1) {
        int t = (threadIdx.x >= off) ? tmp[threadIdx.x - off] : 0;
        __syncthreads();
        tmp[threadIdx.x] += t;
        __syncthreads();
    }
    if (threadIdx.x < nb) bsums[threadIdx.x] = tmp[threadIdx.x] - v;  // exclusive
}

__global__ __launch_bounds__(256) void scan_add_k(int* __restrict__ rp, const int* __restrict__ bsums,
                                                  int n, int E) {
    int i = blockIdx.x * 256 + threadIdx.x;
    if (i < n) rp[i] += bsums[i >> 8];
    if (i == 0) rp[n] = E;
}

__global__ __launch_bounds__(256) void dis_k(const int* __restrict__ rp, float* __restrict__ dis, int n) {
    int i = blockIdx.x * 256 + threadIdx.x;
    if (i < n) dis[i] = rsqrtf((float)(rp[i + 1] - rp[i] + 1));  // +1 self-loop
}

__global__ __launch_bounds__(256) void fill_k(const int* __restrict__ src, const int* __restrict__ dst,
                                              const int* __restrict__ rp, int* __restrict__ cnt,
                                              int* __restrict__ col, float* __restrict__ wgt,
                                              const float* __restrict__ dis, int E) {
    int i = blockIdx.x * 256 + threadIdx.x;
    if (i < E) {
        int s = src[i], d = dst[i];
        int k = atomicSub(&cnt[d], 1) - 1;   // unique slot within row
        int p = rp[d] + k;
        col[p] = s;
        wgt[p] = dis[s] * dis[d];
    }
}

// ---------------- GEMM1: h1 = x @ W1  (N x 128 @ 128 x 64) ----------------

__global__ __launch_bounds__(256) void gemm1_k(const float* __restrict__ x, const float* __restrict__ W1,
                                               float* __restrict__ h1, int n) {
    __shared__ __attribute__((aligned(16))) float xs[64][132];  // +4 pad: bank spread, keeps 16B align
    __shared__ __attribute__((aligned(16))) float ws[128][64];
    int r0b = blockIdx.x * 64;

    // stage W1: 8192 floats = 2048 float4
    const float4* w4 = (const float4*)W1;
    float4* ws4 = (float4*)&ws[0][0];
    for (int i = threadIdx.x; i < 2048; i += 256) ws4[i] = w4[i];
    // stage x tile: 64 rows x 128
    for (int i = threadIdx.x; i < 2048; i += 256) {
        int lin = i * 4;
        int r = lin >> 7, k = lin & 127;
        int gr = r0b + r;
        float4 v = make_float4(0.f, 0.f, 0.f, 0.f);
        if (gr < n) v = ((const float4*)x)[(gr * 128 + k) >> 2];
        *(float4*)&xs[r][k] = v;
    }
    __syncthreads();

    int tx = threadIdx.x & 15, ty = threadIdx.x >> 4;
    int c0 = tx * 4, r0 = ty * 4;
    float acc[4][4] = {};
    for (int k = 0; k < 128; k++) {
        float4 b = *(const float4*)&ws[k][c0];
        float a0 = xs[r0 + 0][k], a1 = xs[r0 + 1][k], a2 = xs[r0 + 2][k], a3 = xs[r0 + 3][k];
        acc[0][0] += a0 * b.x; acc[0][1] += a0 * b.y; acc[0][2] += a0 * b.z; acc[0][3] += a0 * b.w;
        acc[1][0] += a1 * b.x; acc[1][1] += a1 * b.y; acc[1][2] += a1 * b.z; acc[1][3] += a1 * b.w;
        acc[2][0] += a2 * b.x; acc[2][1] += a2 * b.y; acc[2][2] += a2 * b.z; acc[2][3] += a2 * b.w;
        acc[3][0] += a3 * b.x; acc[3][1] += a3 * b.y; acc[3][2] += a3 * b.z; acc[3][3] += a3 * b.w;
    }
    for (int i = 0; i < 4; i++) {
        int gr = r0b + r0 + i;
        if (gr < n)
            *(float4*)&h1[gr * 64 + c0] = make_float4(acc[i][0], acc[i][1], acc[i][2], acc[i][3]);
    }
}

// ---------------- Aggregation layer 1: wave per node, 64 lanes = 64 feats ----------------

__global__ __launch_bounds__(256) void agg1_k(const float* __restrict__ h1, const int* __restrict__ rp,
                                              const int* __restrict__ col, const float* __restrict__ wgt,
                                              const float* __restrict__ dis, float* __restrict__ out, int n) {
    int node = (blockIdx.x * 256 + threadIdx.x) >> 6;
    int f = threadIdx.x & 63;
    if (node >= n) return;
    float d = dis[node];
    float acc = h1[node * 64 + f] * (d * d);   // self-loop
    int e = rp[node], ee = rp[node + 1];
    for (; e + 1 < ee; e += 2) {
        int s0 = col[e], s1 = col[e + 1];
        float w0 = wgt[e], w1 = wgt[e + 1];
        acc += h1[s0 * 64 + f] * w0;
        acc += h1[s1 * 64 + f] * w1;
    }
    if (e < ee) acc += h1[col[e] * 64 + f] * wgt[e];
    out[node * 64 + f] = acc;
}

// ---------------- BN stats ----------------

__global__ __launch_bounds__(256) void bnstats_k(const float* __restrict__ agg1, float* __restrict__ stats, int n) {
    int f = threadIdx.x & 63, g = threadIdx.x >> 6;
    float sum = 0.f, sq = 0.f;
    for (int r = blockIdx.x * 4 + g; r < n; r += gridDim.x * 4) {
        float v = agg1[r * 64 + f];
        sum += v; sq += v * v;
    }
    __shared__ float s1[4][64], s2[4][64];
    s1[g][f] = sum; s2[g][f] = sq;
    __syncthreads();
    if (g == 0) {
        sum = s1[0][f] + s1[1][f] + s1[2][f] + s1[3][f];
        sq  = s2[0][f] + s2[1][f] + s2[2][f] + s2[3][f];
        atomicAdd(&stats[f], sum);
        atomicAdd(&stats[64 + f], sq);
    }
}

// BN folded: h = relu(agg1 * s + t);  b1 cancels in centering (shift invariance).
__global__ __launch_bounds__(64) void bnfin_k(const float* __restrict__ stats, const float* __restrict__ gamma,
                                              const float* __restrict__ beta, float* __restrict__ st, float invn) {
    int f = threadIdx.x;
    if (f < 64) {
        float mean = stats[f] * invn;
        float var = stats[64 + f] * invn - mean * mean;
        float s = gamma[f] * rsqrtf(var + BN_EPS);
        st[f] = s;
        st[64 + f] = beta[f] - mean * s;
    }
}

// ---------------- GEMM2: h2 = relu(agg1*s+t) @ W2  (N x 64 @ 64 x 32) ----------------

__global__ __launch_bounds__(256) void gemm2_k(const float* __restrict__ agg1, const float* __restrict__ W2,
                                               const float* __restrict__ st, float* __restrict__ h2, int n) {
    __shared__ __attribute__((aligned(16))) float xs[64][68];
    __shared__ __attribute__((aligned(16))) float ws2[64][32];
    __shared__ float s_s[64], s_t[64];
    if (threadIdx.x < 64) {
        s_s[threadIdx.x] = st[threadIdx.x];
        s_t[threadIdx.x] = st[64 + threadIdx.x];
    }
    for (int i = threadIdx.x; i < 512; i += 256)
        ((float4*)&ws2[0][0])[i] = ((const float4*)W2)[i];
    __syncthreads();  // s_s/s_t ready before transform below

    int r0b = blockIdx.x * 64;
    for (int i = threadIdx.x; i < 1024; i += 256) {
        int lin = i * 4;
        int r = lin >> 6, k = lin & 63;
        int gr = r0b + r;
        float4 v = make_float4(0.f, 0.f, 0.f, 0.f);
        if (gr < n) v = ((const float4*)agg1)[(gr * 64 + k) >> 2];
        v.x = fmaxf(v.x * s_s[k + 0] + s_t[k + 0], 0.f);
        v.y = fmaxf(v.y * s_s[k + 1] + s_t[k + 1], 0.f);
        v.z = fmaxf(v.z * s_s[k + 2] + s_t[k + 2], 0.f);
        v.w = fmaxf(v.w * s_s[k + 3] + s_t[k + 3], 0.f);
        *(float4*)&xs[r][k] = v;
    }
    __syncthreads();

    int c = threadIdx.x & 31, ty = threadIdx.x >> 5;  // 8 row-groups x 8 rows
    float acc[8] = {};
    for (int k = 0; k < 64; k++) {
        float b = ws2[k][c];
        #pragma unroll
        for (int i = 0; i < 8; i++) acc[i] += xs[ty * 8 + i][k] * b;
    }
    for (int i = 0; i < 8; i++) {
        int gr = r0b + ty * 8 + i;
        if (gr < n) h2[gr * 32 + c] = acc[i];
    }
}

// ---------------- Aggregation layer 2: wave per node, 2 half-waves x 32 feats, + b2 ----------------

__global__ __launch_bounds__(256) void agg2_k(const float* __restrict__ h2, const int* __restrict__ rp,
                                              const int* __restrict__ col, const float* __restrict__ wgt,
                                              const float* __restrict__ dis, const float* __restrict__ b2,
                                              float* __restrict__ out, int n) {
    int node = (blockIdx.x * 256 + threadIdx.x) >> 6;
    int lane = threadIdx.x & 63;
    if (node >= n) return;
    int f = lane & 31, h = lane >> 5;
    float d = dis[node];
    float acc = (h == 0) ? h2[node * 32 + f] * (d * d) : 0.f;   // self-loop on half 0
    int e0 = rp[node], e1 = rp[node + 1];
    for (int e = e0 + h; e < e1; e += 2)
        acc += h2[col[e] * 32 + f] * wgt[e];
    acc += __shfl_down(acc, 32, 64);
    if (h == 0) out[node * 32 + f] = acc + b2[f];
}

// ---------------- launch ----------------

extern "C" void kernel_launch(void* const* d_in, const int* in_sizes, int n_in,
                              void* d_out, int out_size, void* d_ws, size_t ws_size,
                              hipStream_t stream) {
    const float* x      = (const float*)d_in[0];
    const int*   ei     = (const int*)d_in[1];
    const float* W1     = (const float*)d_in[2];
    // d_in[3] = b1 (cancels inside BN)
    const float* gamma1 = (const float*)d_in[4];
    const float* beta1  = (const float*)d_in[5];
    const float* W2     = (const float*)d_in[6];
    const float* b2     = (const float*)d_in[7];
    float* out = (float*)d_out;

    int N = in_sizes[0] / DIN;
    int E = in_sizes[1] / 2;
    const int* src = ei;
    const int* dst = ei + E;

    size_t off = 0;  // in floats/ints (4B units)
    auto alloc = [&](size_t elems) -> void* {
        void* p = (char*)d_ws + off * 4;
        off += (elems + 127) & ~size_t(127);
        return p;
    };
    int*   cnt   = (int*)alloc(N);
    int*   rp    = (int*)alloc((size_t)N + 1);
    float* dis   = (float*)alloc(N);
    int*   bsums = (int*)alloc(512);
    float* stats = (float*)alloc(128);
    float* st    = (float*)alloc(128);
    int*   col   = (int*)alloc(E);
    float* wgt   = (float*)alloc(E);
    float* h1    = (float*)alloc((size_t)N * DH);
    float* agg1  = (float*)alloc((size_t)N * DH);
    float* h2    = h1;  // h1 dead after agg1_k; reuse for h2 (N*32 <= N*64)

    int gE = (E + 255) / 256;
    int gN = (N + 255) / 256;

    hipMemsetAsync(cnt, 0, (size_t)N * sizeof(int), stream);
    hipMemsetAsync(stats, 0, 128 * sizeof(float), stream);

    count_k<<<gE, 256, 0, stream>>>(dst, cnt, E);
    scan_block_k<<<gN, 256, 0, stream>>>(cnt, rp, bsums, N);
    scan_sums_k<<<1, 512, 0, stream>>>(bsums, gN);
    scan_add_k<<<gN, 256, 0, stream>>>(rp, bsums, N, E);
    dis_k<<<gN, 256, 0, stream>>>(rp, dis, N);
    fill_k<<<gE, 256, 0, stream>>>(src, dst, rp, cnt, col, wgt, dis, E);

    gemm1_k<<<(N + 63) / 64, 256, 0, stream>>>(x, W1, h1, N);
    agg1_k<<<(N + 3) / 4, 256, 0, stream>>>(h1, rp, col, wgt, dis, agg1, N);

    bnstats_k<<<400, 256, 0, stream>>>(agg1, stats, N);
    bnfin_k<<<1, 64, 0, stream>>>(stats, gamma1, beta1, st, 1.0f / (float)N);

    gemm2_k<<<(N + 63) / 64, 256, 0, stream>>>(agg1, W2, st, h2, N);
    agg2_k<<<(N + 3) / 4, 256, 0, stream>>>(h2, rp, col, wgt, dis, b2, out, N);
}